// Round 1
// baseline (1156.141 us; speedup 1.0000x reference)
//
#include <hip/hip_runtime.h>
#include <hip/hip_bf16.h>

typedef unsigned short u16;
typedef unsigned int u32;
typedef __bf16 bf16x8 __attribute__((ext_vector_type(8)));
typedef float f32x4 __attribute__((ext_vector_type(4)));

#define SDIM 512
#define BDIM 2
#define DDIM 1024
#define VDIM 32000
#define FCTX 16
#define NROWS (BDIM * SDIM)          // 1024 GEMM M
#define YSTR (SDIM + FCTX - 1)       // 527

__device__ __forceinline__ u16 f2bf(float f) {
    u32 u = __float_as_uint(f);
    u += 0x7fffu + ((u >> 16) & 1u);   // RNE
    return (u16)(u >> 16);
}

__device__ __forceinline__ void gload_lds16(const void* g, void* l) {
    __builtin_amdgcn_global_load_lds((const __attribute__((address_space(1))) void*)g,
                                     (__attribute__((address_space(3))) void*)l, 16, 0, 0);
}

// ---------------- prep: layernorm + bf16 cast of A panels ----------------
__global__ __launch_bounds__(256) void prep_a_kernel(
    const float* __restrict__ emb, const float* __restrict__ lnw,
    u16* __restrict__ Alm, u16* __restrict__ Actx)
{
    int row = blockIdx.x;
    int t = threadIdx.x;
    const float4* x4 = (const float4*)(emb + (size_t)row * DDIM);
    float4 v = x4[t];
    float s1 = v.x + v.y + v.z + v.w;
    float s2 = v.x*v.x + v.y*v.y + v.z*v.z + v.w*v.w;
#pragma unroll
    for (int off = 32; off; off >>= 1) {
        s1 += __shfl_down(s1, off, 64);
        s2 += __shfl_down(s2, off, 64);
    }
    __shared__ float r1[4], r2[4];
    int lane = t & 63, wave = t >> 6;
    if (lane == 0) { r1[wave] = s1; r2[wave] = s2; }
    __syncthreads();
    s1 = r1[0] + r1[1] + r1[2] + r1[3];
    s2 = r2[0] + r2[1] + r2[2] + r2[3];
    float mean = s1 * (1.f / DDIM);
    float var = s2 * (1.f / DDIM) - mean * mean;
    float rstd = rsqrtf(var + 1e-5f);
    float4 w = ((const float4*)lnw)[t];
    ushort4 a, b;
    a.x = f2bf(v.x); a.y = f2bf(v.y); a.z = f2bf(v.z); a.w = f2bf(v.w);
    b.x = f2bf((v.x - mean) * rstd * w.x);
    b.y = f2bf((v.y - mean) * rstd * w.y);
    b.z = f2bf((v.z - mean) * rstd * w.z);
    b.w = f2bf((v.w - mean) * rstd * w.w);
    ((ushort4*)(Alm + (size_t)row * DDIM))[t] = a;
    ((ushort4*)(Actx + (size_t)row * DDIM))[t] = b;
}

// ---------------- cast W fp32 -> bf16 ----------------
__global__ __launch_bounds__(256) void cast_kernel(
    const float4* __restrict__ src, ushort4* __restrict__ dst)
{
    int i = blockIdx.x * 256 + threadIdx.x;   // exactly V*D/4 threads
    float4 f = src[i];
    ushort4 o;
    o.x = f2bf(f.x); o.y = f2bf(f.y); o.z = f2bf(f.z); o.w = f2bf(f.w);
    dst[i] = o;
}

// ---------------- dual GEMM: C[M,N] = A[M,K] * W[N,K]^T (bf16 -> f32) ----------------
// m97 structure: 128x128 tile, BK=32, 4 waves, 4x4 16x16x32 MFMA per wave.
__global__ __launch_bounds__(256) void gemm_kernel(
    const u16* __restrict__ A0, const u16* __restrict__ B0, float* __restrict__ C0,
    const u16* __restrict__ A1, const u16* __restrict__ B1, float* __restrict__ C1)
{
    constexpr int K = DDIM, N = VDIM;
    const u16* A; const u16* Bw; float* C;
    if (blockIdx.z == 0) { A = A0; Bw = B0; C = C0; }
    else                 { A = A1; Bw = B1; C = C1; }

    __shared__ __align__(16) u16 sA[128 * 32];
    __shared__ __align__(16) u16 sB[128 * 32];

    int t = threadIdx.x;
    int lane = t & 63, wave = t >> 6;
    int bm = blockIdx.x, bn = blockIdx.y;

    // staging: thread t loads 16B: row = t/4 (+64), kchunk = t%4; LDS = contiguous t*16B
    const u16* gA = A + (size_t)(bm * 128 + (t >> 2)) * K + (t & 3) * 8;
    const u16* gB = Bw + (size_t)(bn * 128 + (t >> 2)) * K + (t & 3) * 8;
    u16* lA = sA + t * 8;
    u16* lB = sB + t * 8;

    f32x4 acc[4][4] = {};

    int wrow = (wave >> 1) * 64;
    int wcol = (wave & 1) * 64;
    const u16* fA = sA + (wrow + (lane & 15)) * 32 + (lane >> 4) * 8;
    const u16* fB = sB + (wcol + (lane & 15)) * 32 + (lane >> 4) * 8;

    for (int kt = 0; kt < K; kt += 32) {
        gload_lds16(gA,           lA);
        gload_lds16(gA + 64 * K,  lA + 2048);
        gload_lds16(gB,           lB);
        gload_lds16(gB + 64 * K,  lB + 2048);
        gA += 32; gB += 32;
        __syncthreads();   // drains vmcnt before barrier -> staging visible
        bf16x8 af[4], bfr[4];
#pragma unroll
        for (int i = 0; i < 4; ++i) af[i] = *(const bf16x8*)(fA + i * 16 * 32);
#pragma unroll
        for (int j = 0; j < 4; ++j) bfr[j] = *(const bf16x8*)(fB + j * 16 * 32);
#pragma unroll
        for (int i = 0; i < 4; ++i)
#pragma unroll
            for (int j = 0; j < 4; ++j)
                acc[i][j] = __builtin_amdgcn_mfma_f32_16x16x32_bf16(af[i], bfr[j], acc[i][j], 0, 0, 0);
        __syncthreads();   // protect LDS from next iter's staging
    }

    // epilogue: D row = quad*4+r, col = lane&15
    int q = lane >> 4, lr = lane & 15;
    int row0 = bm * 128 + wrow + q * 4;
    int col0 = bn * 128 + wcol + lr;
#pragma unroll
    for (int i = 0; i < 4; ++i)
#pragma unroll
        for (int j = 0; j < 4; ++j) {
            float* cp = C + (size_t)(row0 + i * 16) * N + col0 + j * 16;
#pragma unroll
            for (int r = 0; r < 4; ++r) cp[(size_t)r * N] = acc[i][j][r];
        }
}

// ---------------- conv (exp-decay causal window) + softplus-sum ----------------
__global__ __launch_bounds__(256) void conv_kernel(
    const float* __restrict__ c, float* __restrict__ logits, float* __restrict__ acc)
{
    int v = blockIdx.x * 256 + threadIdx.x;   // 0..31999
    int b = blockIdx.y;
    float coef[FCTX];
    float Z = 0.f;
#pragma unroll
    for (int i = 0; i < FCTX; ++i) { coef[i] = expf(-0.5f * i); Z += coef[i]; }
    float invZ = 1.f / Z;
#pragma unroll
    for (int i = 0; i < FCTX; ++i) coef[i] *= invZ;

    float ring[FCTX];
#pragma unroll
    for (int i = 0; i < FCTX; ++i) ring[i] = 0.f;

    float sp = 0.f;
    size_t base = ((size_t)b * SDIM) * VDIM + v;
    for (int s0 = 0; s0 < SDIM; s0 += FCTX) {
#pragma unroll
        for (int u = 0; u < FCTX; ++u) {
            size_t off = base + (size_t)(s0 + u) * VDIM;
            float cv = c[off];
            ring[u] = cv;
            float ctx = 0.f;
#pragma unroll
            for (int i = 0; i < FCTX; ++i) ctx += coef[i] * ring[(u - i) & (FCTX - 1)];
            logits[off] += ctx;
            sp += fmaxf(cv, 0.f) + log1pf(expf(-fabsf(cv)));   // softplus(cv)
        }
    }
    // block reduce sp -> one atomic
#pragma unroll
    for (int off = 32; off; off >>= 1) sp += __shfl_down(sp, off, 64);
    __shared__ float rs[4];
    int lane = threadIdx.x & 63, wave = threadIdx.x >> 6;
    if (lane == 0) rs[wave] = sp;
    __syncthreads();
    if (threadIdx.x == 0) atomicAdd(acc + 1, rs[0] + rs[1] + rs[2] + rs[3]);
}

// ---------------- BCE correction terms (t=1 entries + duplicate weights) ----------------
__device__ __forceinline__ float softplus(float x) {
    return fmaxf(x, 0.f) + log1pf(expf(-fabsf(x)));
}

__global__ __launch_bounds__(256) void corr_kernel(
    const float* __restrict__ c, const int* __restrict__ y, float* __restrict__ acc)
{
    int sid = blockIdx.x * 256 + threadIdx.x;
    float corr = 0.f;
    if (sid < SDIM) {
        int tok[2 * FCTX];
        for (int i = 0; i < FCTX; ++i) {
            tok[i] = y[sid + i];
            tok[FCTX + i] = y[YSTR + sid + i];
        }
        for (int k = 0; k < 2 * FCTX; ++k) {
            int v = tok[k];
            bool seen = false;
            for (int j = 0; j < k; ++j) seen |= (tok[j] == v);
            if (seen) continue;
            int c0 = 0, c1 = 0;
            for (int i = 0; i < FCTX; ++i) {
                c0 += (tok[i] == v);
                c1 += (tok[FCTX + i] == v);
            }
            float w = ((c0 > 1) || (c1 > 1)) ? 1.5f : 1.0f;
            float cv0 = c[(size_t)sid * VDIM + v];
            float cv1 = c[(size_t)(SDIM + sid) * VDIM + v];
            if (w > 1.f) corr += 0.5f * (softplus(cv0) + softplus(cv1));
            if (c0 > 0) corr -= w * cv0;
            if (c1 > 0) corr -= w * cv1;
        }
    }
    atomicAdd(acc + 1, corr);
}

// ---------------- NLL over final logits (online softmax) ----------------
__global__ __launch_bounds__(256) void loss_kernel(
    const float* __restrict__ logits, const int* __restrict__ y, float* __restrict__ acc)
{
    int row = blockIdx.x;  // 0..1023
    int t = threadIdx.x;
    const float* lp = logits + (size_t)row * VDIM;
    float m = -3.4e38f, sum = 0.f;
    for (int i = t; i < VDIM; i += 256) {
        float x = lp[i];
        float nm = fmaxf(m, x);
        sum = sum * expf(m - nm) + expf(x - nm);
        m = nm;
    }
#pragma unroll
    for (int off = 32; off; off >>= 1) {
        float om = __shfl_down(m, off, 64);
        float os = __shfl_down(sum, off, 64);
        float nm = fmaxf(m, om);
        sum = sum * expf(m - nm) + os * expf(om - nm);
        m = nm;
    }
    __shared__ float sm[4], ss[4];
    int lane = t & 63, wave = t >> 6;
    if (lane == 0) { sm[wave] = m; ss[wave] = sum; }
    __syncthreads();
    if (t == 0) {
        float M = sm[0], S = ss[0];
        for (int wv = 1; wv < 4; ++wv) {
            float nm = fmaxf(M, sm[wv]);
            S = S * expf(M - nm) + ss[wv] * expf(sm[wv] - nm);
            M = nm;
        }
        int b = row >> 9, s = row & 511;
        int tgt = y[b * YSTR + s];
        float xt = lp[tgt];
        atomicAdd(acc, -(xt - M - logf(S)));
    }
}

__global__ void finalize_kernel(const float* __restrict__ acc, float* __restrict__ out)
{
    out[(size_t)NROWS * VDIM]     = acc[0] * (1.f / (float)NROWS);
    out[(size_t)NROWS * VDIM + 1] = acc[1] * (1.f / ((float)NROWS * (float)VDIM));
}

extern "C" void kernel_launch(void* const* d_in, const int* in_sizes, int n_in,
                              void* d_out, int out_size, void* d_ws, size_t ws_size,
                              hipStream_t stream)
{
    const float* emb  = (const float*)d_in[0];
    const float* Wlm  = (const float*)d_in[1];
    const float* Wctx = (const float*)d_in[2];
    const float* lnw  = (const float*)d_in[3];
    const int*   y    = (const int*)d_in[4];
    float* out = (float*)d_out;

    // ws layout (all 16B aligned)
    char* ws = (char*)d_ws;
    const size_t A_BYTES = (size_t)NROWS * DDIM * 2;       // 2 MB each
    const size_t W_BYTES = (size_t)VDIM * DDIM * 2;        // 65.536 MB each
    const size_t C_BYTES = (size_t)NROWS * VDIM * 4;       // 131.072 MB
    u16*   Alm   = (u16*)ws;
    u16*   Actx  = (u16*)(ws + A_BYTES);
    u16*   WlmB  = (u16*)(ws + 2 * A_BYTES);
    u16*   WctxB = (u16*)(ws + 2 * A_BYTES + W_BYTES);
    float* c     = (float*)(ws + 2 * A_BYTES + 2 * W_BYTES);
    float* acc   = (float*)(ws + 2 * A_BYTES + 2 * W_BYTES + C_BYTES);

    hipMemsetAsync(acc, 0, 2 * sizeof(float), stream);
    prep_a_kernel<<<NROWS, 256, 0, stream>>>(emb, lnw, Alm, Actx);
    cast_kernel<<<(VDIM * DDIM / 4) / 256, 256, 0, stream>>>((const float4*)Wlm,  (ushort4*)WlmB);
    cast_kernel<<<(VDIM * DDIM / 4) / 256, 256, 0, stream>>>((const float4*)Wctx, (ushort4*)WctxB);
    gemm_kernel<<<dim3(NROWS / 128, VDIM / 128, 2), 256, 0, stream>>>(Alm, WlmB, out, Actx, WctxB, c);
    conv_kernel<<<dim3(VDIM / 256, BDIM), 256, 0, stream>>>(c, out, acc);
    corr_kernel<<<2, 256, 0, stream>>>(c, y, acc);
    loss_kernel<<<NROWS, 256, 0, stream>>>(out, y, acc);
    finalize_kernel<<<1, 1, 0, stream>>>(acc, out);
}